// Round 3
// baseline (633.593 us; speedup 1.0000x reference)
//
#include <hip/hip_runtime.h>
#include <hip/hip_bf16.h>
#include <stdint.h>

#define N_TOK 2048
#define HID   2048
#define NEXP  8
#define DFF   1408

typedef __attribute__((ext_vector_type(8))) short short8;
typedef __attribute__((ext_vector_type(4))) float f32x4;

__device__ __forceinline__ unsigned short f2bf(float f) {
  union { float ff; uint32_t u; } v; v.ff = f;
  return (unsigned short)((v.u + 0x7FFFu + ((v.u >> 16) & 1u)) >> 16);
}

// async global->LDS, 16B per lane; LDS dest = base + lane*16 (wave-uniform base)
__device__ __forceinline__ void gl2lds16(const void* g, void* l) {
  __builtin_amdgcn_global_load_lds(
      (const __attribute__((address_space(1))) void*)g,
      (__attribute__((address_space(3))) void*)l, 16, 0, 0);
}

// ---------------- K1: gating (fp32 logits -> softmax -> top2) ----------------
__global__ __launch_bounds__(256) void gate_topk_k(
    const float* __restrict__ h, const float* __restrict__ gw,
    int* __restrict__ cnt, int* __restrict__ topk_idx, float* __restrict__ topk_w)
{
  int token = blockIdx.x * 4 + (threadIdx.x >> 6);
  int lane  = threadIdx.x & 63;
  const float* hr = h + (size_t)token * HID;
  float acc[NEXP];
#pragma unroll
  for (int e = 0; e < NEXP; ++e) acc[e] = 0.f;
  for (int i = lane; i < HID; i += 64) {
    float hv = hr[i];
#pragma unroll
    for (int e = 0; e < NEXP; ++e) acc[e] = fmaf(hv, gw[e * HID + i], acc[e]);
  }
#pragma unroll
  for (int e = 0; e < NEXP; ++e) {
    float a = acc[e];
#pragma unroll
    for (int s = 32; s > 0; s >>= 1) a += __shfl_xor(a, s, 64);
    acc[e] = a;
  }
  if (lane == 0) {
    float m = acc[0];
#pragma unroll
    for (int e = 1; e < NEXP; ++e) m = fmaxf(m, acc[e]);
    float w[NEXP]; float s = 0.f;
#pragma unroll
    for (int e = 0; e < NEXP; ++e) { w[e] = __expf(acc[e] - m); s += w[e]; }
    float inv = 1.f / s;
    int i0 = 0; float b0 = acc[0];
#pragma unroll
    for (int e = 1; e < NEXP; ++e) if (acc[e] > b0) { b0 = acc[e]; i0 = e; }
    int i1 = -1; float b1 = -3.4e38f;
#pragma unroll
    for (int e = 0; e < NEXP; ++e) if (e != i0 && acc[e] > b1) { b1 = acc[e]; i1 = e; }
    topk_idx[token * 2 + 0] = i0;
    topk_idx[token * 2 + 1] = i1;
    topk_w[token * 2 + 0] = w[i0] * inv;
    topk_w[token * 2 + 1] = w[i1] * inv;
    atomicAdd(&cnt[i0], 1);
    atomicAdd(&cnt[i1], 1);
  }
}

// ---------------- K2: prefix ----------------
__global__ void prefix_k(const int* __restrict__ cnt, int* __restrict__ offs,
                         int* __restrict__ cursor) {
  if (threadIdx.x == 0 && blockIdx.x == 0) {
    int s = 0;
    for (int e = 0; e < NEXP; ++e) { offs[e] = s; cursor[e] = s; s += cnt[e]; }
  }
}

// ---------------- K3: scatter ----------------
__global__ __launch_bounds__(256) void scatter_k(
    const int* __restrict__ topk_idx, const float* __restrict__ topk_w,
    int* __restrict__ cursor, int* __restrict__ pair_token, float* __restrict__ pair_w)
{
  int n = blockIdx.x * 256 + threadIdx.x;
  if (n >= N_TOK) return;
#pragma unroll
  for (int k = 0; k < 2; ++k) {
    int e = topk_idx[n * 2 + k];
    int p = atomicAdd(&cursor[e], 1);
    pair_token[p] = n;
    pair_w[p] = topk_w[n * 2 + k];
  }
}

// ---------------- K4: h fp32 -> bf16 ----------------
__global__ __launch_bounds__(256) void convert_h_k(const float* __restrict__ src,
                                                   unsigned short* __restrict__ dst) {
  int i = blockIdx.x * 256 + threadIdx.x;
  float4 a = ((const float4*)src)[(size_t)i * 2];
  float4 b = ((const float4*)src)[(size_t)i * 2 + 1];
  unsigned short o[8] = {f2bf(a.x), f2bf(a.y), f2bf(a.z), f2bf(a.w),
                         f2bf(b.x), f2bf(b.y), f2bf(b.z), f2bf(b.w)};
  *(short8*)&dst[(size_t)i * 8] = *(const short8*)o;
}

// ---------------- K5: transpose-convert  src fp32 [z][R][C] -> dst bf16 [z][C][R] ----------------
// dual-source variant: z < nz1 reads s1/d1, else s2/d2 (merges wg+wu into one launch)
__global__ __launch_bounds__(256) void transpose_k(const float* __restrict__ s1,
                                                   unsigned short* __restrict__ d1,
                                                   const float* __restrict__ s2,
                                                   unsigned short* __restrict__ d2,
                                                   int R, int C, int nz1)
{
  __shared__ unsigned short T[64 * 66];
  const size_t sl = (size_t)R * C;
  int z = blockIdx.z;
  const float* s; unsigned short* d;
  if (z < nz1) { s = s1 + (size_t)z * sl; d = d1 + (size_t)z * sl; }
  else { s = s2 + (size_t)(z - nz1) * sl; d = d2 + (size_t)(z - nz1) * sl; }
  const int rb = blockIdx.x * 64, cb = blockIdx.y * 64;
  const int t = threadIdx.x;
  const int tr = t >> 4, tc = (t & 15) * 4;
  const float* sp = s + (size_t)(rb + tr) * C + cb + tc;
#pragma unroll
  for (int i = 0; i < 4; ++i) {
    float4 v = *(const float4*)(sp + (size_t)i * 16 * C);
    int r = tr + i * 16;
    uint32_t p0 = (uint32_t)f2bf(v.x) | ((uint32_t)f2bf(v.y) << 16);
    uint32_t p1 = (uint32_t)f2bf(v.z) | ((uint32_t)f2bf(v.w) << 16);
    *(uint32_t*)&T[r * 66 + tc]     = p0;
    *(uint32_t*)&T[r * 66 + tc + 2] = p1;
  }
  __syncthreads();
  const int f = t >> 2, ch = (t & 3) * 16;
  unsigned short* dp = d + (size_t)(cb + f) * R + rb + ch;
#pragma unroll
  for (int g = 0; g < 2; ++g) {
    unsigned short buf[8];
#pragma unroll
    for (int j = 0; j < 8; ++j) buf[j] = T[(ch + g * 8 + j) * 66 + f];
    *(short8*)(dp + g * 8) = *(const short8*)buf;
  }
}

// ---------------- K6: grouped GEMM gate+up (M128 x N128 x BK64, 8 waves) ----------------
// 2-phase double-buffered schedule: STAGE(next) -> compute(cur) -> one barrier.
__global__ __launch_bounds__(512) void gateup3_k(
    const unsigned short* __restrict__ hbf,
    const unsigned short* __restrict__ wgt, const unsigned short* __restrict__ wut,
    const int* __restrict__ cnt, const int* __restrict__ offs,
    const int* __restrict__ pair_token, unsigned short* __restrict__ act,
    int e_base, size_t wstride)
{
  const int ez = blockIdx.z, e = e_base + ez;
  const int count = cnt[e], mb = blockIdx.x;
  if (mb * 128 >= count) return;
  const int off = offs[e];
  const int rows = min(128, count - mb * 128);
  const int c0 = blockIdx.y * 128;

  __shared__ unsigned short As[2][128 * 64];
  __shared__ unsigned short Bg[2][128 * 64];
  __shared__ unsigned short Bu[2][128 * 64];
  __shared__ int tok[128];

  const int t = threadIdx.x;
  if (t < 128) tok[t] = pair_token[off + mb * 128 + min(t, rows - 1)];
  __syncthreads();

  const int w = t >> 6, l = t & 63;
  const int sr = l >> 3;                       // row-within-8-group
  const int sc = ((l & 7) ^ sr) * 8;           // swizzled source col (bf16 elems)
  const int r0 = w * 16 + sr, r1 = w * 16 + 8 + sr;

  const unsigned short* wgE = wgt + (size_t)ez * wstride;
  const unsigned short* wuE = wut + (size_t)ez * wstride;
  const unsigned short* aP0 = hbf + (size_t)tok[r0] * HID + sc;
  const unsigned short* aP1 = hbf + (size_t)tok[r1] * HID + sc;
  const unsigned short* gP0 = wgE + (size_t)(c0 + r0) * HID + sc;
  const unsigned short* gP1 = wgE + (size_t)(c0 + r1) * HID + sc;
  const unsigned short* uP0 = wuE + (size_t)(c0 + r0) * HID + sc;
  const unsigned short* uP1 = wuE + (size_t)(c0 + r1) * HID + sc;
  const int ldsLo = (w * 16) * 64, ldsHi = (w * 16 + 8) * 64;

  const int fr = l & 15, fq = l >> 4;
  const int wr = (w >> 2) * 64, wc = (w & 3) * 32;
  const int f3 = fr & 7;

  f32x4 accg[4][2], accu[4][2];
#pragma unroll
  for (int i = 0; i < 4; ++i)
#pragma unroll
    for (int j = 0; j < 2; ++j) {
      accg[i][j] = (f32x4){0.f, 0.f, 0.f, 0.f};
      accu[i][j] = (f32x4){0.f, 0.f, 0.f, 0.f};
    }

  auto stage = [&](int b, int kt) {
    gl2lds16(aP0 + kt, &As[b][ldsLo]); gl2lds16(aP1 + kt, &As[b][ldsHi]);
    gl2lds16(gP0 + kt, &Bg[b][ldsLo]); gl2lds16(gP1 + kt, &Bg[b][ldsHi]);
    gl2lds16(uP0 + kt, &Bu[b][ldsLo]); gl2lds16(uP1 + kt, &Bu[b][ldsHi]);
  };
  auto compute = [&](int b) {
    short8 af[4][2], bg[2][2], bu[2][2];
#pragma unroll
    for (int kk = 0; kk < 2; ++kk) {
      const int ch = ((kk * 4 + fq) ^ f3) * 8;
#pragma unroll
      for (int mi = 0; mi < 4; ++mi)
        af[mi][kk] = *(const short8*)&As[b][(wr + mi * 16 + fr) * 64 + ch];
#pragma unroll
      for (int ni = 0; ni < 2; ++ni) {
        bg[ni][kk] = *(const short8*)&Bg[b][(wc + ni * 16 + fr) * 64 + ch];
        bu[ni][kk] = *(const short8*)&Bu[b][(wc + ni * 16 + fr) * 64 + ch];
      }
    }
#pragma unroll
    for (int kk = 0; kk < 2; ++kk)
#pragma unroll
      for (int mi = 0; mi < 4; ++mi)
#pragma unroll
        for (int ni = 0; ni < 2; ++ni) {
          accg[mi][ni] = __builtin_amdgcn_mfma_f32_16x16x32_bf16(af[mi][kk], bg[ni][kk], accg[mi][ni], 0, 0, 0);
          accu[mi][ni] = __builtin_amdgcn_mfma_f32_16x16x32_bf16(af[mi][kk], bu[ni][kk], accu[mi][ni], 0, 0, 0);
        }
  };

  stage(0, 0);
  __syncthreads();
  int cur = 0;
  for (int kt = 64; kt < HID; kt += 64) {
    stage(cur ^ 1, kt);   // next tile in flight; barrier's vmcnt(0) is the wait
    compute(cur);
    __syncthreads();
    cur ^= 1;
  }
  compute(cur);

#pragma unroll
  for (int mi = 0; mi < 4; ++mi)
#pragma unroll
    for (int ni = 0; ni < 2; ++ni)
#pragma unroll
      for (int j = 0; j < 4; ++j) {
        int r = wr + mi * 16 + fq * 4 + j;
        if (r < rows) {
          float g = accg[mi][ni][j], u = accu[mi][ni][j];
          float a = (g / (1.f + __expf(-g))) * u;
          act[(size_t)(off + mb * 128 + r) * DFF + (c0 + wc + ni * 16 + fr)] = f2bf(a);
        }
      }
}

// ---------------- K7: grouped GEMM down (M128 x N128 x BK64, 4 waves), 2-phase ----------------
__global__ __launch_bounds__(256) void down3_k(
    const unsigned short* __restrict__ act, const unsigned short* __restrict__ wdt,
    const int* __restrict__ cnt, const int* __restrict__ offs,
    const int* __restrict__ pair_token, const float* __restrict__ pair_w,
    float* __restrict__ out, int e_base, size_t wstride)
{
  const int ez = blockIdx.z, e = e_base + ez;
  const int count = cnt[e], mb = blockIdx.x;
  if (mb * 128 >= count) return;
  const int off = offs[e];
  const int rows = min(128, count - mb * 128);
  const int c0 = blockIdx.y * 128;

  __shared__ unsigned short As[2][128 * 64];
  __shared__ unsigned short Bd[2][128 * 64];
  __shared__ int tok2[128];
  __shared__ float twt[128];

  const int t = threadIdx.x;
  if (t < 128) {
    int rc = min(t, rows - 1);
    tok2[t] = pair_token[off + mb * 128 + rc];
    twt[t] = pair_w[off + mb * 128 + rc];
  }
  __syncthreads();

  const int w = t >> 6, l = t & 63;
  const int sr = l >> 3;
  const int sc = ((l & 7) ^ sr) * 8;
  const unsigned short* wdE = wdt + (size_t)ez * wstride;

  const unsigned short* aP[4];
  const unsigned short* bP[4];
  int ldsB[4];
#pragma unroll
  for (int i = 0; i < 4; ++i) {
    int rr = w * 32 + i * 8 + sr;   // 0..127
    aP[i] = act + (size_t)(off + mb * 128 + rr) * DFF + sc;
    bP[i] = wdE + (size_t)(c0 + rr) * DFF + sc;
    ldsB[i] = (w * 32 + i * 8) * 64;  // wave-uniform base
  }

  const int fr = l & 15, fq = l >> 4;
  const int wr = (w >> 1) * 64, wc = (w & 1) * 64;
  const int f3 = fr & 7;

  f32x4 acc[4][4];
#pragma unroll
  for (int i = 0; i < 4; ++i)
#pragma unroll
    for (int j = 0; j < 4; ++j) acc[i][j] = (f32x4){0.f, 0.f, 0.f, 0.f};

  auto stage = [&](int b, int kt) {
#pragma unroll
    for (int i = 0; i < 4; ++i) {
      gl2lds16(aP[i] + kt, &As[b][ldsB[i]]);
      gl2lds16(bP[i] + kt, &Bd[b][ldsB[i]]);
    }
  };
  auto compute = [&](int b) {
    short8 af[4][2], bd[4][2];
#pragma unroll
    for (int kk = 0; kk < 2; ++kk) {
      const int ch = ((kk * 4 + fq) ^ f3) * 8;
#pragma unroll
      for (int mi = 0; mi < 4; ++mi)
        af[mi][kk] = *(const short8*)&As[b][(wr + mi * 16 + fr) * 64 + ch];
#pragma unroll
      for (int ni = 0; ni < 4; ++ni)
        bd[ni][kk] = *(const short8*)&Bd[b][(wc + ni * 16 + fr) * 64 + ch];
    }
#pragma unroll
    for (int kk = 0; kk < 2; ++kk)
#pragma unroll
      for (int mi = 0; mi < 4; ++mi)
#pragma unroll
        for (int ni = 0; ni < 4; ++ni)
          acc[mi][ni] = __builtin_amdgcn_mfma_f32_16x16x32_bf16(af[mi][kk], bd[ni][kk], acc[mi][ni], 0, 0, 0);
  };

  stage(0, 0);
  __syncthreads();
  int cur = 0;
  for (int kt = 64; kt < DFF; kt += 64) {
    stage(cur ^ 1, kt);
    compute(cur);
    __syncthreads();
    cur ^= 1;
  }
  compute(cur);

#pragma unroll
  for (int mi = 0; mi < 4; ++mi)
#pragma unroll
    for (int ni = 0; ni < 4; ++ni)
#pragma unroll
      for (int j = 0; j < 4; ++j) {
        int r = wr + mi * 16 + fq * 4 + j;
        if (r < rows) {
          float v = acc[mi][ni][j] * twt[r];
          atomicAdd(&out[(size_t)tok2[r] * HID + (c0 + wc + ni * 16 + fr)], v);
        }
      }
}

extern "C" void kernel_launch(void* const* d_in, const int* in_sizes, int n_in,
                              void* d_out, int out_size, void* d_ws, size_t ws_size,
                              hipStream_t stream) {
  const float* h  = (const float*)d_in[0];
  const float* gw = (const float*)d_in[1];
  const float* wg = (const float*)d_in[2];
  const float* wu = (const float*)d_in[3];
  const float* wd = (const float*)d_in[4];
  float* out = (float*)d_out;

  const size_t SL = (size_t)DFF * HID;
  char* ws = (char*)d_ws;
  int*   cnt        = (int*)(ws + 0);
  int*   offs       = (int*)(ws + 32);
  int*   cursor     = (int*)(ws + 64);
  int*   pair_token = (int*)(ws + 256);
  float* pair_w     = (float*)(ws + 256 + 16384);
  int*   topk_idx   = (int*)(ws + 33024);
  float* topk_w     = (float*)(ws + 49408);
  unsigned short* act = (unsigned short*)(ws + 65792);                 // 11,534,336 B
  unsigned short* hbf = (unsigned short*)(ws + 11600128);              //  8,388,608 B
  unsigned short* wgt = (unsigned short*)(ws + 19988736);              // 46,137,344 B (also wdt)
  unsigned short* wut = (unsigned short*)(ws + 66126080);              // 46,137,344 B
  const size_t NEED_FULL = 112263424ull;

  hipMemsetAsync(ws, 0, 256, stream);
  hipMemsetAsync(d_out, 0, (size_t)out_size * sizeof(float), stream);

  gate_topk_k<<<N_TOK / 4, 256, 0, stream>>>(h, gw, cnt, topk_idx, topk_w);
  prefix_k<<<1, 64, 0, stream>>>(cnt, offs, cursor);
  scatter_k<<<N_TOK / 256, 256, 0, stream>>>(topk_idx, topk_w, cursor, pair_token, pair_w);
  convert_h_k<<<(N_TOK * HID / 8) / 256, 256, 0, stream>>>(h, hbf);

  if (ws_size >= NEED_FULL) {
    transpose_k<<<dim3(HID / 64, DFF / 64, 16), 256, 0, stream>>>(wg, wgt, wu, wut, HID, DFF, 8);
    gateup3_k<<<dim3(16, DFF / 128, 8), 512, 0, stream>>>(hbf, wgt, wut, cnt, offs,
                                                          pair_token, act, 0, SL);
    transpose_k<<<dim3(DFF / 64, HID / 64, 8), 256, 0, stream>>>(wd, wgt, wd, wgt, DFF, HID, 8);
    down3_k<<<dim3(16, HID / 128, 8), 256, 0, stream>>>(act, wgt, cnt, offs,
                                                        pair_token, pair_w, out, 0, SL);
  } else {
    unsigned short* wgtE = (unsigned short*)(ws + 19988736);
    unsigned short* wutE = (unsigned short*)(ws + 19988736 + 5767168);
    for (int e = 0; e < NEXP; ++e) {
      transpose_k<<<dim3(HID / 64, DFF / 64, 2), 256, 0, stream>>>(wg + e * SL, wgtE, wu + e * SL, wutE, HID, DFF, 1);
      gateup3_k<<<dim3(16, DFF / 128, 1), 512, 0, stream>>>(hbf, wgtE, wutE, cnt, offs,
                                                            pair_token, act, e, 0);
    }
    for (int e = 0; e < NEXP; ++e) {
      transpose_k<<<dim3(DFF / 64, HID / 64, 1), 256, 0, stream>>>(wd + e * SL, wgtE, wd + e * SL, wgtE, DFF, HID, 1);
      down3_k<<<dim3(16, HID / 128, 1), 256, 0, stream>>>(act, wgtE, cnt, offs,
                                                          pair_token, pair_w, out, e, 0);
    }
  }
}

// Round 4
// 329.750 us; speedup vs baseline: 1.9214x; 1.9214x over previous
//
#include <hip/hip_runtime.h>
#include <hip/hip_bf16.h>
#include <stdint.h>

#define N_TOK 2048
#define HID   2048
#define NEXP  8
#define DFF   1408

typedef __attribute__((ext_vector_type(8))) short short8;
typedef __attribute__((ext_vector_type(4))) float f32x4;

__device__ __forceinline__ unsigned short f2bf(float f) {
  union { float ff; uint32_t u; } v; v.ff = f;
  return (unsigned short)((v.u + 0x7FFFu + ((v.u >> 16) & 1u)) >> 16);
}

__device__ __forceinline__ void gl2lds16(const void* g, void* l) {
  __builtin_amdgcn_global_load_lds(
      (const __attribute__((address_space(1))) void*)g,
      (__attribute__((address_space(3))) void*)l, 16, 0, 0);
}

// ---------------- K1: gating ----------------
__global__ __launch_bounds__(256) void gate_topk_k(
    const float* __restrict__ h, const float* __restrict__ gw,
    int* __restrict__ cnt, int* __restrict__ topk_idx, float* __restrict__ topk_w)
{
  int token = blockIdx.x * 4 + (threadIdx.x >> 6);
  int lane  = threadIdx.x & 63;
  const float* hr = h + (size_t)token * HID;
  float acc[NEXP];
#pragma unroll
  for (int e = 0; e < NEXP; ++e) acc[e] = 0.f;
  for (int i = lane; i < HID; i += 64) {
    float hv = hr[i];
#pragma unroll
    for (int e = 0; e < NEXP; ++e) acc[e] = fmaf(hv, gw[e * HID + i], acc[e]);
  }
#pragma unroll
  for (int e = 0; e < NEXP; ++e) {
    float a = acc[e];
#pragma unroll
    for (int s = 32; s > 0; s >>= 1) a += __shfl_xor(a, s, 64);
    acc[e] = a;
  }
  if (lane == 0) {
    float m = acc[0];
#pragma unroll
    for (int e = 1; e < NEXP; ++e) m = fmaxf(m, acc[e]);
    float w[NEXP]; float s = 0.f;
#pragma unroll
    for (int e = 0; e < NEXP; ++e) { w[e] = __expf(acc[e] - m); s += w[e]; }
    float inv = 1.f / s;
    int i0 = 0; float b0 = acc[0];
#pragma unroll
    for (int e = 1; e < NEXP; ++e) if (acc[e] > b0) { b0 = acc[e]; i0 = e; }
    int i1 = -1; float b1 = -3.4e38f;
#pragma unroll
    for (int e = 0; e < NEXP; ++e) if (e != i0 && acc[e] > b1) { b1 = acc[e]; i1 = e; }
    topk_idx[token * 2 + 0] = i0;
    topk_idx[token * 2 + 1] = i1;
    topk_w[token * 2 + 0] = w[i0] * inv;
    topk_w[token * 2 + 1] = w[i1] * inv;
    atomicAdd(&cnt[i0], 1);
    atomicAdd(&cnt[i1], 1);
  }
}

// ---------------- K2: prefix ----------------
__global__ void prefix_k(const int* __restrict__ cnt, int* __restrict__ offs,
                         int* __restrict__ cursor) {
  if (threadIdx.x == 0 && blockIdx.x == 0) {
    int s = 0;
    for (int e = 0; e < NEXP; ++e) { offs[e] = s; cursor[e] = s; s += cnt[e]; }
  }
}

// ---------------- K3: scatter (+ inverse map tok_slot) ----------------
__global__ __launch_bounds__(256) void scatter_k(
    const int* __restrict__ topk_idx, const float* __restrict__ topk_w,
    int* __restrict__ cursor, int* __restrict__ pair_token, float* __restrict__ pair_w,
    int* __restrict__ tok_slot)
{
  int n = blockIdx.x * 256 + threadIdx.x;
  if (n >= N_TOK) return;
#pragma unroll
  for (int k = 0; k < 2; ++k) {
    int e = topk_idx[n * 2 + k];
    int p = atomicAdd(&cursor[e], 1);
    pair_token[p] = n;
    pair_w[p] = topk_w[n * 2 + k];
    tok_slot[n * 2 + k] = p;
  }
}

// ---------------- K4: h fp32 -> bf16 ----------------
__global__ __launch_bounds__(256) void convert_h_k(const float* __restrict__ src,
                                                   unsigned short* __restrict__ dst) {
  int i = blockIdx.x * 256 + threadIdx.x;
  float4 a = ((const float4*)src)[(size_t)i * 2];
  float4 b = ((const float4*)src)[(size_t)i * 2 + 1];
  unsigned short o[8] = {f2bf(a.x), f2bf(a.y), f2bf(a.z), f2bf(a.w),
                         f2bf(b.x), f2bf(b.y), f2bf(b.z), f2bf(b.w)};
  *(short8*)&dst[(size_t)i * 8] = *(const short8*)o;
}

// ---------------- K5: transpose-convert fp32 [z][R][C] -> bf16 [z][C][R] ----------------
__global__ __launch_bounds__(256) void transpose_k(const float* __restrict__ s1,
                                                   unsigned short* __restrict__ d1,
                                                   const float* __restrict__ s2,
                                                   unsigned short* __restrict__ d2,
                                                   int R, int C, int nz1)
{
  __shared__ unsigned short T[64 * 66];
  const size_t sl = (size_t)R * C;
  int z = blockIdx.z;
  const float* s; unsigned short* d;
  if (z < nz1) { s = s1 + (size_t)z * sl; d = d1 + (size_t)z * sl; }
  else { s = s2 + (size_t)(z - nz1) * sl; d = d2 + (size_t)(z - nz1) * sl; }
  const int rb = blockIdx.x * 64, cb = blockIdx.y * 64;
  const int t = threadIdx.x;
  const int tr = t >> 4, tc = (t & 15) * 4;
  const float* sp = s + (size_t)(rb + tr) * C + cb + tc;
#pragma unroll
  for (int i = 0; i < 4; ++i) {
    float4 v = *(const float4*)(sp + (size_t)i * 16 * C);
    int r = tr + i * 16;
    uint32_t p0 = (uint32_t)f2bf(v.x) | ((uint32_t)f2bf(v.y) << 16);
    uint32_t p1 = (uint32_t)f2bf(v.z) | ((uint32_t)f2bf(v.w) << 16);
    *(uint32_t*)&T[r * 66 + tc]     = p0;
    *(uint32_t*)&T[r * 66 + tc + 2] = p1;
  }
  __syncthreads();
  const int f = t >> 2, ch = (t & 3) * 16;
  unsigned short* dp = d + (size_t)(cb + f) * R + rb + ch;
#pragma unroll
  for (int g = 0; g < 2; ++g) {
    unsigned short buf[8];
#pragma unroll
    for (int j = 0; j < 8; ++j) buf[j] = T[(ch + g * 8 + j) * 66 + f];
    *(short8*)(dp + g * 8) = *(const short8*)buf;
  }
}

// ---------------- K6: grouped GEMM gate+up (128x128xBK64, 8 waves, single-buf) ----
// tile queue: x = w + mb*nw ; nw % 8 == 0 so all mb-replicas of weight tile w
// land on the same XCD, and weight tiles spread across XCDs by w%8.
__global__ __launch_bounds__(512) void gateup4_k(
    const unsigned short* __restrict__ hbf,
    const unsigned short* __restrict__ wgt, const unsigned short* __restrict__ wut,
    const int* __restrict__ cnt, const int* __restrict__ offs,
    const int* __restrict__ pair_token, unsigned short* __restrict__ act,
    int e_fixed, int nw, int nbcnt, size_t wstride)
{
  const int x = blockIdx.x;
  const int wti = x % nw, mb = x / nw;
  int e, nb;
  if (e_fixed >= 0) { e = e_fixed; nb = wti; }
  else { e = wti / nbcnt; nb = wti % nbcnt; }
  const int count = cnt[e];
  if (mb * 128 >= count) return;
  const int off = offs[e];
  const int rows = min(128, count - mb * 128);
  const int c0 = nb * 128;

  __shared__ unsigned short As[128 * 64];
  __shared__ unsigned short Bg[128 * 64];
  __shared__ unsigned short Bu[128 * 64];
  __shared__ int tok[128];

  const int t = threadIdx.x;
  if (t < 128) tok[t] = pair_token[off + mb * 128 + min(t, rows - 1)];
  __syncthreads();

  const int w = t >> 6, l = t & 63;
  const int sr = l >> 3;
  const int sc = ((l & 7) ^ sr) * 8;
  const int r0 = w * 16 + sr, r1 = w * 16 + 8 + sr;

  const size_t wb = (e_fixed >= 0) ? 0 : (size_t)e * wstride;
  const unsigned short* wgE = wgt + wb;
  const unsigned short* wuE = wut + wb;
  const unsigned short* aP0 = hbf + (size_t)tok[r0] * HID + sc;
  const unsigned short* aP1 = hbf + (size_t)tok[r1] * HID + sc;
  const unsigned short* gP0 = wgE + (size_t)(c0 + r0) * HID + sc;
  const unsigned short* gP1 = wgE + (size_t)(c0 + r1) * HID + sc;
  const unsigned short* uP0 = wuE + (size_t)(c0 + r0) * HID + sc;
  const unsigned short* uP1 = wuE + (size_t)(c0 + r1) * HID + sc;
  const int ldsLo = (w * 16) * 64, ldsHi = (w * 16 + 8) * 64;

  const int fr = l & 15, fq = l >> 4;
  const int wr = (w >> 2) * 64, wc = (w & 3) * 32;
  const int f3 = fr & 7;

  f32x4 accg[4][2], accu[4][2];
#pragma unroll
  for (int i = 0; i < 4; ++i)
#pragma unroll
    for (int j = 0; j < 2; ++j) {
      accg[i][j] = (f32x4){0.f, 0.f, 0.f, 0.f};
      accu[i][j] = (f32x4){0.f, 0.f, 0.f, 0.f};
    }

  for (int kt = 0; kt < HID; kt += 64) {
    gl2lds16(aP0 + kt, &As[ldsLo]); gl2lds16(aP1 + kt, &As[ldsHi]);
    gl2lds16(gP0 + kt, &Bg[ldsLo]); gl2lds16(gP1 + kt, &Bg[ldsHi]);
    gl2lds16(uP0 + kt, &Bu[ldsLo]); gl2lds16(uP1 + kt, &Bu[ldsHi]);
    __syncthreads();

    short8 af[4][2], bg[2][2], bu[2][2];
#pragma unroll
    for (int kk = 0; kk < 2; ++kk) {
      const int ch = ((kk * 4 + fq) ^ f3) * 8;
#pragma unroll
      for (int mi = 0; mi < 4; ++mi)
        af[mi][kk] = *(const short8*)&As[(wr + mi * 16 + fr) * 64 + ch];
#pragma unroll
      for (int ni = 0; ni < 2; ++ni) {
        bg[ni][kk] = *(const short8*)&Bg[(wc + ni * 16 + fr) * 64 + ch];
        bu[ni][kk] = *(const short8*)&Bu[(wc + ni * 16 + fr) * 64 + ch];
      }
    }
#pragma unroll
    for (int kk = 0; kk < 2; ++kk)
#pragma unroll
      for (int mi = 0; mi < 4; ++mi)
#pragma unroll
        for (int ni = 0; ni < 2; ++ni) {
          accg[mi][ni] = __builtin_amdgcn_mfma_f32_16x16x32_bf16(af[mi][kk], bg[ni][kk], accg[mi][ni], 0, 0, 0);
          accu[mi][ni] = __builtin_amdgcn_mfma_f32_16x16x32_bf16(af[mi][kk], bu[ni][kk], accu[mi][ni], 0, 0, 0);
        }
    __syncthreads();
  }

#pragma unroll
  for (int mi = 0; mi < 4; ++mi)
#pragma unroll
    for (int ni = 0; ni < 2; ++ni)
#pragma unroll
      for (int j = 0; j < 4; ++j) {
        int r = wr + mi * 16 + fq * 4 + j;
        if (r < rows) {
          float g = accg[mi][ni][j], u = accu[mi][ni][j];
          float a = (g / (1.f + __expf(-g))) * u;
          act[(size_t)(off + mb * 128 + r) * DFF + (c0 + wc + ni * 16 + fr)] = f2bf(a);
        }
      }
}

// ---------------- K7: grouped GEMM down -> pair-major y (no atomics) ----------------
__global__ __launch_bounds__(256) void down4_k(
    const unsigned short* __restrict__ act, const unsigned short* __restrict__ wdt,
    const int* __restrict__ cnt, const int* __restrict__ offs,
    float* __restrict__ ypair, int e_fixed, int nw, int nbcnt, size_t wstride)
{
  const int x = blockIdx.x;
  const int wti = x % nw, mb = x / nw;
  int e, nb;
  if (e_fixed >= 0) { e = e_fixed; nb = wti; }
  else { e = wti / nbcnt; nb = wti % nbcnt; }
  const int count = cnt[e];
  if (mb * 128 >= count) return;
  const int off = offs[e];
  const int rows = min(128, count - mb * 128);
  const int c0 = nb * 128;

  __shared__ unsigned short As[128 * 64];
  __shared__ unsigned short Bd[128 * 64];

  const int t = threadIdx.x;
  const int w = t >> 6, l = t & 63;
  const int sr = l >> 3;
  const int sc = ((l & 7) ^ sr) * 8;
  const size_t wb = (e_fixed >= 0) ? 0 : (size_t)e * wstride;
  const unsigned short* wdE = wdt + wb;

  const unsigned short* aP[4];
  const unsigned short* bP[4];
  int ldsB[4];
#pragma unroll
  for (int i = 0; i < 4; ++i) {
    int rr = w * 32 + i * 8 + sr;
    aP[i] = act + (size_t)(off + mb * 128 + rr) * DFF + sc;
    bP[i] = wdE + (size_t)(c0 + rr) * DFF + sc;
    ldsB[i] = (w * 32 + i * 8) * 64;
  }

  const int fr = l & 15, fq = l >> 4;
  const int wr = (w >> 1) * 64, wc = (w & 1) * 64;
  const int f3 = fr & 7;

  f32x4 acc[4][4];
#pragma unroll
  for (int i = 0; i < 4; ++i)
#pragma unroll
    for (int j = 0; j < 4; ++j) acc[i][j] = (f32x4){0.f, 0.f, 0.f, 0.f};

  for (int kt = 0; kt < DFF; kt += 64) {
#pragma unroll
    for (int i = 0; i < 4; ++i) {
      gl2lds16(aP[i] + kt, &As[ldsB[i]]);
      gl2lds16(bP[i] + kt, &Bd[ldsB[i]]);
    }
    __syncthreads();

    short8 af[4][2], bd[4][2];
#pragma unroll
    for (int kk = 0; kk < 2; ++kk) {
      const int ch = ((kk * 4 + fq) ^ f3) * 8;
#pragma unroll
      for (int mi = 0; mi < 4; ++mi)
        af[mi][kk] = *(const short8*)&As[(wr + mi * 16 + fr) * 64 + ch];
#pragma unroll
      for (int ni = 0; ni < 4; ++ni)
        bd[ni][kk] = *(const short8*)&Bd[(wc + ni * 16 + fr) * 64 + ch];
    }
#pragma unroll
    for (int kk = 0; kk < 2; ++kk)
#pragma unroll
      for (int mi = 0; mi < 4; ++mi)
#pragma unroll
        for (int ni = 0; ni < 4; ++ni)
          acc[mi][ni] = __builtin_amdgcn_mfma_f32_16x16x32_bf16(af[mi][kk], bd[ni][kk], acc[mi][ni], 0, 0, 0);
    __syncthreads();
  }

#pragma unroll
  for (int mi = 0; mi < 4; ++mi)
#pragma unroll
    for (int ni = 0; ni < 4; ++ni)
#pragma unroll
      for (int j = 0; j < 4; ++j) {
        int r = wr + mi * 16 + fq * 4 + j;
        if (r < rows)
          ypair[(size_t)(off + mb * 128 + r) * HID + (c0 + wc + ni * 16 + fr)] = acc[mi][ni][j];
      }
}

// ---------------- K8: weighted combine  out[n] = w0*y[s0] + w1*y[s1] ----------------
__global__ __launch_bounds__(256) void combine_k(
    const float* __restrict__ ypair, const int* __restrict__ tok_slot,
    const float* __restrict__ topk_w, float* __restrict__ out)
{
  int i = blockIdx.x * 256 + threadIdx.x;      // over N_TOK * HID/4
  int n = i >> (11 - 2);                        // HID/4 = 512 per token
  int dv = (i & 511) * 4;
  int s0 = tok_slot[n * 2], s1 = tok_slot[n * 2 + 1];
  float w0 = topk_w[n * 2], w1 = topk_w[n * 2 + 1];
  float4 a = *(const float4*)&ypair[(size_t)s0 * HID + dv];
  float4 b = *(const float4*)&ypair[(size_t)s1 * HID + dv];
  float4 o;
  o.x = w0 * a.x + w1 * b.x; o.y = w0 * a.y + w1 * b.y;
  o.z = w0 * a.z + w1 * b.z; o.w = w0 * a.w + w1 * b.w;
  *(float4*)&out[(size_t)n * HID + dv] = o;
}

extern "C" void kernel_launch(void* const* d_in, const int* in_sizes, int n_in,
                              void* d_out, int out_size, void* d_ws, size_t ws_size,
                              hipStream_t stream) {
  const float* h  = (const float*)d_in[0];
  const float* gw = (const float*)d_in[1];
  const float* wg = (const float*)d_in[2];
  const float* wu = (const float*)d_in[3];
  const float* wd = (const float*)d_in[4];
  float* out = (float*)d_out;

  const size_t SL = (size_t)DFF * HID;
  char* ws = (char*)d_ws;
  int*   cnt        = (int*)(ws + 0);
  int*   offs       = (int*)(ws + 32);
  int*   cursor     = (int*)(ws + 64);
  int*   pair_token = (int*)(ws + 256);
  float* pair_w     = (float*)(ws + 16640);
  int*   tok_slot   = (int*)(ws + 33024);
  int*   topk_idx   = (int*)(ws + 49408);
  float* topk_w     = (float*)(ws + 65792);
  unsigned short* act = (unsigned short*)(ws + 82176);                // 11,534,336
  unsigned short* hbf = (unsigned short*)(ws + 11616512);             //  8,388,608
  unsigned short* wgt = (unsigned short*)(ws + 20005120);             // 46,137,344 (also wd^T)
  unsigned short* wut = (unsigned short*)(ws + 66142464);             // 46,137,344
  float* ypair_full   = (float*)(ws + 66142464);                      // aliases wut (down phase)
  const size_t NEED_FULL = 112279808ull;

  hipMemsetAsync(ws, 0, 256, stream);

  gate_topk_k<<<N_TOK / 4, 256, 0, stream>>>(h, gw, cnt, topk_idx, topk_w);
  prefix_k<<<1, 64, 0, stream>>>(cnt, offs, cursor);
  scatter_k<<<N_TOK / 256, 256, 0, stream>>>(topk_idx, topk_w, cursor, pair_token, pair_w, tok_slot);
  convert_h_k<<<(N_TOK * HID / 8) / 256, 256, 0, stream>>>(h, hbf);

  if (ws_size >= NEED_FULL) {
    transpose_k<<<dim3(HID / 64, DFF / 64, 16), 256, 0, stream>>>(wg, wgt, wu, wut, HID, DFF, 8);
    gateup4_k<<<88 * 16, 512, 0, stream>>>(hbf, wgt, wut, cnt, offs, pair_token, act,
                                           -1, 88, 11, SL);
    transpose_k<<<dim3(DFF / 64, HID / 64, 8), 256, 0, stream>>>(wd, wgt, wd, wgt, DFF, HID, 8);
    down4_k<<<128 * 16, 256, 0, stream>>>(act, wgt, cnt, offs, ypair_full,
                                          -1, 128, 16, SL);
    combine_k<<<(N_TOK * HID / 4) / 256, 256, 0, stream>>>(ypair_full, tok_slot, topk_w, out);
  } else {
    // per-expert fallback (~65 MB peak)
    unsigned short* wgtE = (unsigned short*)(ws + 20005120);          // 5,767,168
    unsigned short* wutE = (unsigned short*)(ws + 25772288);          // 5,767,168
    float* ypair = (float*)(ws + 31539456);                           // 33,554,432
    for (int e = 0; e < NEXP; ++e) {
      transpose_k<<<dim3(HID / 64, DFF / 64, 2), 256, 0, stream>>>(wg + e * SL, wgtE, wu + e * SL, wutE, HID, DFF, 1);
      gateup4_k<<<11 * 16, 512, 0, stream>>>(hbf, wgtE, wutE, cnt, offs, pair_token, act,
                                             e, 11, 11, 0);
    }
    for (int e = 0; e < NEXP; ++e) {
      transpose_k<<<dim3(DFF / 64, HID / 64, 1), 256, 0, stream>>>(wd + e * SL, wgtE, wd + e * SL, wgtE, DFF, HID, 1);
      down4_k<<<16 * 16, 256, 0, stream>>>(act, wgtE, cnt, offs, ypair, e, 16, 16, 0);
    }
    combine_k<<<(N_TOK * HID / 4) / 256, 256, 0, stream>>>(ypair, tok_slot, topk_w, out);
  }
}

// Round 5
// 322.388 us; speedup vs baseline: 1.9653x; 1.0228x over previous
//
#include <hip/hip_runtime.h>
#include <hip/hip_bf16.h>
#include <stdint.h>

#define N_TOK 2048
#define HID   2048
#define NEXP  8
#define DFF   1408

typedef __attribute__((ext_vector_type(8))) short short8;
typedef __attribute__((ext_vector_type(4))) float f32x4;

__device__ __forceinline__ unsigned short f2bf(float f) {
  union { float ff; uint32_t u; } v; v.ff = f;
  return (unsigned short)((v.u + 0x7FFFu + ((v.u >> 16) & 1u)) >> 16);
}

__device__ __forceinline__ void gl2lds16(const void* g, void* l) {
  __builtin_amdgcn_global_load_lds(
      (const __attribute__((address_space(1))) void*)g,
      (__attribute__((address_space(3))) void*)l, 16, 0, 0);
}

// ---------------- K1: gating ----------------
__global__ __launch_bounds__(256) void gate_topk_k(
    const float* __restrict__ h, const float* __restrict__ gw,
    int* __restrict__ cnt, int* __restrict__ topk_idx, float* __restrict__ topk_w)
{
  int token = blockIdx.x * 4 + (threadIdx.x >> 6);
  int lane  = threadIdx.x & 63;
  const float* hr = h + (size_t)token * HID;
  float acc[NEXP];
#pragma unroll
  for (int e = 0; e < NEXP; ++e) acc[e] = 0.f;
  for (int i = lane; i < HID; i += 64) {
    float hv = hr[i];
#pragma unroll
    for (int e = 0; e < NEXP; ++e) acc[e] = fmaf(hv, gw[e * HID + i], acc[e]);
  }
#pragma unroll
  for (int e = 0; e < NEXP; ++e) {
    float a = acc[e];
#pragma unroll
    for (int s = 32; s > 0; s >>= 1) a += __shfl_xor(a, s, 64);
    acc[e] = a;
  }
  if (lane == 0) {
    float m = acc[0];
#pragma unroll
    for (int e = 1; e < NEXP; ++e) m = fmaxf(m, acc[e]);
    float w[NEXP]; float s = 0.f;
#pragma unroll
    for (int e = 0; e < NEXP; ++e) { w[e] = __expf(acc[e] - m); s += w[e]; }
    float inv = 1.f / s;
    int i0 = 0; float b0 = acc[0];
#pragma unroll
    for (int e = 1; e < NEXP; ++e) if (acc[e] > b0) { b0 = acc[e]; i0 = e; }
    int i1 = -1; float b1 = -3.4e38f;
#pragma unroll
    for (int e = 0; e < NEXP; ++e) if (e != i0 && acc[e] > b1) { b1 = acc[e]; i1 = e; }
    topk_idx[token * 2 + 0] = i0;
    topk_idx[token * 2 + 1] = i1;
    topk_w[token * 2 + 0] = w[i0] * inv;
    topk_w[token * 2 + 1] = w[i1] * inv;
    atomicAdd(&cnt[i0], 1);
    atomicAdd(&cnt[i1], 1);
  }
}

// ---------------- K2: prefix ----------------
__global__ void prefix_k(const int* __restrict__ cnt, int* __restrict__ offs,
                         int* __restrict__ cursor) {
  if (threadIdx.x == 0 && blockIdx.x == 0) {
    int s = 0;
    for (int e = 0; e < NEXP; ++e) { offs[e] = s; cursor[e] = s; s += cnt[e]; }
  }
}

// ---------------- K3: scatter (+ inverse map tok_slot) ----------------
__global__ __launch_bounds__(256) void scatter_k(
    const int* __restrict__ topk_idx, const float* __restrict__ topk_w,
    int* __restrict__ cursor, int* __restrict__ pair_token, float* __restrict__ pair_w,
    int* __restrict__ tok_slot)
{
  int n = blockIdx.x * 256 + threadIdx.x;
  if (n >= N_TOK) return;
#pragma unroll
  for (int k = 0; k < 2; ++k) {
    int e = topk_idx[n * 2 + k];
    int p = atomicAdd(&cursor[e], 1);
    pair_token[p] = n;
    pair_w[p] = topk_w[n * 2 + k];
    tok_slot[n * 2 + k] = p;
  }
}

// ---------------- K4: h fp32 -> bf16 ----------------
__global__ __launch_bounds__(256) void convert_h_k(const float* __restrict__ src,
                                                   unsigned short* __restrict__ dst) {
  int i = blockIdx.x * 256 + threadIdx.x;
  float4 a = ((const float4*)src)[(size_t)i * 2];
  float4 b = ((const float4*)src)[(size_t)i * 2 + 1];
  unsigned short o[8] = {f2bf(a.x), f2bf(a.y), f2bf(a.z), f2bf(a.w),
                         f2bf(b.x), f2bf(b.y), f2bf(b.z), f2bf(b.w)};
  *(short8*)&dst[(size_t)i * 8] = *(const short8*)o;
}

// ---------------- K5: transpose-convert fp32 [z][R][C] -> bf16 [z][C][R] ----------------
__global__ __launch_bounds__(256) void transpose_k(const float* __restrict__ s1,
                                                   unsigned short* __restrict__ d1,
                                                   const float* __restrict__ s2,
                                                   unsigned short* __restrict__ d2,
                                                   int R, int C, int nz1)
{
  __shared__ unsigned short T[64 * 66];
  const size_t sl = (size_t)R * C;
  int z = blockIdx.z;
  const float* s; unsigned short* d;
  if (z < nz1) { s = s1 + (size_t)z * sl; d = d1 + (size_t)z * sl; }
  else { s = s2 + (size_t)(z - nz1) * sl; d = d2 + (size_t)(z - nz1) * sl; }
  const int rb = blockIdx.x * 64, cb = blockIdx.y * 64;
  const int t = threadIdx.x;
  const int tr = t >> 4, tc = (t & 15) * 4;
  const float* sp = s + (size_t)(rb + tr) * C + cb + tc;
#pragma unroll
  for (int i = 0; i < 4; ++i) {
    float4 v = *(const float4*)(sp + (size_t)i * 16 * C);
    int r = tr + i * 16;
    uint32_t p0 = (uint32_t)f2bf(v.x) | ((uint32_t)f2bf(v.y) << 16);
    uint32_t p1 = (uint32_t)f2bf(v.z) | ((uint32_t)f2bf(v.w) << 16);
    *(uint32_t*)&T[r * 66 + tc]     = p0;
    *(uint32_t*)&T[r * 66 + tc + 2] = p1;
  }
  __syncthreads();
  const int f = t >> 2, ch = (t & 3) * 16;
  unsigned short* dp = d + (size_t)(cb + f) * R + rb + ch;
#pragma unroll
  for (int g = 0; g < 2; ++g) {
    unsigned short buf[8];
#pragma unroll
    for (int j = 0; j < 8; ++j) buf[j] = T[(ch + g * 8 + j) * 66 + f];
    *(short8*)(dp + g * 8) = *(const short8*)buf;
  }
}

// ---------------- K6: grouped GEMM gate+up (128x128xBK64, 8 waves) ----------------
// dbuf + counted vmcnt: stage(next) -> vmcnt(6)[old tile] -> s_barrier -> MFMA -> s_barrier.
// Loads stay in flight across the barrier (T3/T4). Tile-queue XCD mapping as before.
__global__ __launch_bounds__(512) void gateup5_k(
    const unsigned short* __restrict__ hbf,
    const unsigned short* __restrict__ wgt, const unsigned short* __restrict__ wut,
    const int* __restrict__ cnt, const int* __restrict__ offs,
    const int* __restrict__ pair_token, unsigned short* __restrict__ act,
    int e_fixed, int nw, int nbcnt, size_t wstride)
{
  const int x = blockIdx.x;
  const int wti = x % nw, mb = x / nw;
  int e, nb;
  if (e_fixed >= 0) { e = e_fixed; nb = wti; }
  else { e = wti / nbcnt; nb = wti % nbcnt; }
  const int count = cnt[e];
  if (mb * 128 >= count) return;
  const int off = offs[e];
  const int rows = min(128, count - mb * 128);
  const int c0 = nb * 128;

  __shared__ unsigned short As[2][128 * 64];
  __shared__ unsigned short Bg[2][128 * 64];
  __shared__ unsigned short Bu[2][128 * 64];
  __shared__ int tok[128];

  const int t = threadIdx.x;
  if (t < 128) tok[t] = pair_token[off + mb * 128 + min(t, rows - 1)];
  __syncthreads();

  const int w = t >> 6, l = t & 63;
  const int sr = l >> 3;
  const int sc = ((l & 7) ^ sr) * 8;
  const int r0 = w * 16 + sr, r1 = w * 16 + 8 + sr;

  const size_t wb = (e_fixed >= 0) ? 0 : (size_t)e * wstride;
  const unsigned short* wgE = wgt + wb;
  const unsigned short* wuE = wut + wb;
  const unsigned short* aP0 = hbf + (size_t)tok[r0] * HID + sc;
  const unsigned short* aP1 = hbf + (size_t)tok[r1] * HID + sc;
  const unsigned short* gP0 = wgE + (size_t)(c0 + r0) * HID + sc;
  const unsigned short* gP1 = wgE + (size_t)(c0 + r1) * HID + sc;
  const unsigned short* uP0 = wuE + (size_t)(c0 + r0) * HID + sc;
  const unsigned short* uP1 = wuE + (size_t)(c0 + r1) * HID + sc;
  const int ldsLo = (w * 16) * 64, ldsHi = (w * 16 + 8) * 64;

  const int fr = l & 15, fq = l >> 4;
  const int wr = (w >> 2) * 64, wc = (w & 3) * 32;
  const int f3 = fr & 7;

  f32x4 accg[4][2], accu[4][2];
#pragma unroll
  for (int i = 0; i < 4; ++i)
#pragma unroll
    for (int j = 0; j < 2; ++j) {
      accg[i][j] = (f32x4){0.f, 0.f, 0.f, 0.f};
      accu[i][j] = (f32x4){0.f, 0.f, 0.f, 0.f};
    }

  auto stage = [&](int b, int kt) {
    gl2lds16(aP0 + kt, &As[b][ldsLo]); gl2lds16(aP1 + kt, &As[b][ldsHi]);
    gl2lds16(gP0 + kt, &Bg[b][ldsLo]); gl2lds16(gP1 + kt, &Bg[b][ldsHi]);
    gl2lds16(uP0 + kt, &Bu[b][ldsLo]); gl2lds16(uP1 + kt, &Bu[b][ldsHi]);
  };
  auto compute = [&](int b) {
    short8 af[4][2], bg[2][2], bu[2][2];
#pragma unroll
    for (int kk = 0; kk < 2; ++kk) {
      const int ch = ((kk * 4 + fq) ^ f3) * 8;
#pragma unroll
      for (int mi = 0; mi < 4; ++mi)
        af[mi][kk] = *(const short8*)&As[b][(wr + mi * 16 + fr) * 64 + ch];
#pragma unroll
      for (int ni = 0; ni < 2; ++ni) {
        bg[ni][kk] = *(const short8*)&Bg[b][(wc + ni * 16 + fr) * 64 + ch];
        bu[ni][kk] = *(const short8*)&Bu[b][(wc + ni * 16 + fr) * 64 + ch];
      }
    }
    __builtin_amdgcn_s_setprio(1);
#pragma unroll
    for (int kk = 0; kk < 2; ++kk)
#pragma unroll
      for (int mi = 0; mi < 4; ++mi)
#pragma unroll
        for (int ni = 0; ni < 2; ++ni) {
          accg[mi][ni] = __builtin_amdgcn_mfma_f32_16x16x32_bf16(af[mi][kk], bg[ni][kk], accg[mi][ni], 0, 0, 0);
          accu[mi][ni] = __builtin_amdgcn_mfma_f32_16x16x32_bf16(af[mi][kk], bu[ni][kk], accu[mi][ni], 0, 0, 0);
        }
    __builtin_amdgcn_s_setprio(0);
  };

  const int NK = HID / 64;     // 32
  stage(0, 0);
  int cur = 0;
  for (int k = 0; k + 1 < NK; ++k) {
    stage(cur ^ 1, (k + 1) * 64);                  // next tile in flight
    asm volatile("s_waitcnt vmcnt(6)" ::: "memory"); // old tile complete; 6 newer outstanding
    asm volatile("s_barrier" ::: "memory");
    compute(cur);
    asm volatile("s_barrier" ::: "memory");        // all waves done reading cur
    cur ^= 1;
  }
  asm volatile("s_waitcnt vmcnt(0)" ::: "memory");
  asm volatile("s_barrier" ::: "memory");
  compute(cur);

#pragma unroll
  for (int mi = 0; mi < 4; ++mi)
#pragma unroll
    for (int ni = 0; ni < 2; ++ni)
#pragma unroll
      for (int j = 0; j < 4; ++j) {
        int r = wr + mi * 16 + fq * 4 + j;
        if (r < rows) {
          float g = accg[mi][ni][j], u = accu[mi][ni][j];
          float a = (g / (1.f + __expf(-g))) * u;
          act[(size_t)(off + mb * 128 + r) * DFF + (c0 + wc + ni * 16 + fr)] = f2bf(a);
        }
      }
}

// ---------------- K7: grouped GEMM down -> pair-major y (dbuf + counted vmcnt) ----------------
__global__ __launch_bounds__(256) void down5_k(
    const unsigned short* __restrict__ act, const unsigned short* __restrict__ wdt,
    const int* __restrict__ cnt, const int* __restrict__ offs,
    float* __restrict__ ypair, int e_fixed, int nw, int nbcnt, size_t wstride)
{
  const int x = blockIdx.x;
  const int wti = x % nw, mb = x / nw;
  int e, nb;
  if (e_fixed >= 0) { e = e_fixed; nb = wti; }
  else { e = wti / nbcnt; nb = wti % nbcnt; }
  const int count = cnt[e];
  if (mb * 128 >= count) return;
  const int off = offs[e];
  const int rows = min(128, count - mb * 128);
  const int c0 = nb * 128;

  __shared__ unsigned short As[2][128 * 64];
  __shared__ unsigned short Bd[2][128 * 64];

  const int t = threadIdx.x;
  const int w = t >> 6, l = t & 63;
  const int sr = l >> 3;
  const int sc = ((l & 7) ^ sr) * 8;
  const size_t wb = (e_fixed >= 0) ? 0 : (size_t)e * wstride;
  const unsigned short* wdE = wdt + wb;

  const unsigned short* aP[4];
  const unsigned short* bP[4];
  int ldsB[4];
#pragma unroll
  for (int i = 0; i < 4; ++i) {
    int rr = w * 32 + i * 8 + sr;
    aP[i] = act + (size_t)(off + mb * 128 + rr) * DFF + sc;
    bP[i] = wdE + (size_t)(c0 + rr) * DFF + sc;
    ldsB[i] = (w * 32 + i * 8) * 64;
  }

  const int fr = l & 15, fq = l >> 4;
  const int wr = (w >> 1) * 64, wc = (w & 1) * 64;
  const int f3 = fr & 7;

  f32x4 acc[4][4];
#pragma unroll
  for (int i = 0; i < 4; ++i)
#pragma unroll
    for (int j = 0; j < 4; ++j) acc[i][j] = (f32x4){0.f, 0.f, 0.f, 0.f};

  auto stage = [&](int b, int kt) {
#pragma unroll
    for (int i = 0; i < 4; ++i) {
      gl2lds16(aP[i] + kt, &As[b][ldsB[i]]);
      gl2lds16(bP[i] + kt, &Bd[b][ldsB[i]]);
    }
  };
  auto compute = [&](int b) {
    short8 af[4][2], bd[4][2];
#pragma unroll
    for (int kk = 0; kk < 2; ++kk) {
      const int ch = ((kk * 4 + fq) ^ f3) * 8;
#pragma unroll
      for (int mi = 0; mi < 4; ++mi)
        af[mi][kk] = *(const short8*)&As[b][(wr + mi * 16 + fr) * 64 + ch];
#pragma unroll
      for (int ni = 0; ni < 4; ++ni)
        bd[ni][kk] = *(const short8*)&Bd[b][(wc + ni * 16 + fr) * 64 + ch];
    }
    __builtin_amdgcn_s_setprio(1);
#pragma unroll
    for (int kk = 0; kk < 2; ++kk)
#pragma unroll
      for (int mi = 0; mi < 4; ++mi)
#pragma unroll
        for (int ni = 0; ni < 4; ++ni)
          acc[mi][ni] = __builtin_amdgcn_mfma_f32_16x16x32_bf16(af[mi][kk], bd[ni][kk], acc[mi][ni], 0, 0, 0);
    __builtin_amdgcn_s_setprio(0);
  };

  const int NK = DFF / 64;     // 22
  stage(0, 0);
  int cur = 0;
  for (int k = 0; k + 1 < NK; ++k) {
    stage(cur ^ 1, (k + 1) * 64);
    asm volatile("s_waitcnt vmcnt(8)" ::: "memory");
    asm volatile("s_barrier" ::: "memory");
    compute(cur);
    asm volatile("s_barrier" ::: "memory");
    cur ^= 1;
  }
  asm volatile("s_waitcnt vmcnt(0)" ::: "memory");
  asm volatile("s_barrier" ::: "memory");
  compute(cur);

#pragma unroll
  for (int mi = 0; mi < 4; ++mi)
#pragma unroll
    for (int ni = 0; ni < 4; ++ni)
#pragma unroll
      for (int j = 0; j < 4; ++j) {
        int r = wr + mi * 16 + fq * 4 + j;
        if (r < rows)
          ypair[(size_t)(off + mb * 128 + r) * HID + (c0 + wc + ni * 16 + fr)] = acc[mi][ni][j];
      }
}

// ---------------- K8: weighted combine ----------------
__global__ __launch_bounds__(256) void combine_k(
    const float* __restrict__ ypair, const int* __restrict__ tok_slot,
    const float* __restrict__ topk_w, float* __restrict__ out)
{
  int i = blockIdx.x * 256 + threadIdx.x;
  int n = i >> 9;
  int dv = (i & 511) * 4;
  int s0 = tok_slot[n * 2], s1 = tok_slot[n * 2 + 1];
  float w0 = topk_w[n * 2], w1 = topk_w[n * 2 + 1];
  float4 a = *(const float4*)&ypair[(size_t)s0 * HID + dv];
  float4 b = *(const float4*)&ypair[(size_t)s1 * HID + dv];
  float4 o;
  o.x = w0 * a.x + w1 * b.x; o.y = w0 * a.y + w1 * b.y;
  o.z = w0 * a.z + w1 * b.z; o.w = w0 * a.w + w1 * b.w;
  *(float4*)&out[(size_t)n * HID + dv] = o;
}

extern "C" void kernel_launch(void* const* d_in, const int* in_sizes, int n_in,
                              void* d_out, int out_size, void* d_ws, size_t ws_size,
                              hipStream_t stream) {
  const float* h  = (const float*)d_in[0];
  const float* gw = (const float*)d_in[1];
  const float* wg = (const float*)d_in[2];
  const float* wu = (const float*)d_in[3];
  const float* wd = (const float*)d_in[4];
  float* out = (float*)d_out;

  const size_t SL = (size_t)DFF * HID;
  char* ws = (char*)d_ws;
  int*   cnt        = (int*)(ws + 0);
  int*   offs       = (int*)(ws + 32);
  int*   cursor     = (int*)(ws + 64);
  int*   pair_token = (int*)(ws + 256);
  float* pair_w     = (float*)(ws + 16640);
  int*   tok_slot   = (int*)(ws + 33024);
  int*   topk_idx   = (int*)(ws + 49408);
  float* topk_w     = (float*)(ws + 65792);
  unsigned short* act = (unsigned short*)(ws + 82176);                // 11,534,336
  unsigned short* hbf = (unsigned short*)(ws + 11616512);             //  8,388,608
  unsigned short* wgt = (unsigned short*)(ws + 20005120);             // 46,137,344 (also wd^T)
  unsigned short* wut = (unsigned short*)(ws + 66142464);             // 46,137,344
  float* ypair_full   = (float*)(ws + 66142464);                      // aliases wut (down phase)
  const size_t NEED_FULL = 112279808ull;

  hipMemsetAsync(ws, 0, 256, stream);

  gate_topk_k<<<N_TOK / 4, 256, 0, stream>>>(h, gw, cnt, topk_idx, topk_w);
  prefix_k<<<1, 64, 0, stream>>>(cnt, offs, cursor);
  scatter_k<<<N_TOK / 256, 256, 0, stream>>>(topk_idx, topk_w, cursor, pair_token, pair_w, tok_slot);
  convert_h_k<<<(N_TOK * HID / 8) / 256, 256, 0, stream>>>(h, hbf);

  if (ws_size >= NEED_FULL) {
    transpose_k<<<dim3(HID / 64, DFF / 64, 16), 256, 0, stream>>>(wg, wgt, wu, wut, HID, DFF, 8);
    gateup5_k<<<88 * 16, 512, 0, stream>>>(hbf, wgt, wut, cnt, offs, pair_token, act,
                                           -1, 88, 11, SL);
    transpose_k<<<dim3(DFF / 64, HID / 64, 8), 256, 0, stream>>>(wd, wgt, wd, wgt, DFF, HID, 8);
    down5_k<<<128 * 16, 256, 0, stream>>>(act, wgt, cnt, offs, ypair_full,
                                          -1, 128, 16, SL);
    combine_k<<<(N_TOK * HID / 4) / 256, 256, 0, stream>>>(ypair_full, tok_slot, topk_w, out);
  } else {
    unsigned short* wgtE = (unsigned short*)(ws + 20005120);
    unsigned short* wutE = (unsigned short*)(ws + 25772288);
    float* ypair = (float*)(ws + 31539456);
    for (int e = 0; e < NEXP; ++e) {
      transpose_k<<<dim3(HID / 64, DFF / 64, 2), 256, 0, stream>>>(wg + e * SL, wgtE, wu + e * SL, wutE, HID, DFF, 1);
      gateup5_k<<<11 * 16, 512, 0, stream>>>(hbf, wgtE, wutE, cnt, offs, pair_token, act,
                                             e, 11, 11, 0);
    }
    for (int e = 0; e < NEXP; ++e) {
      transpose_k<<<dim3(DFF / 64, HID / 64, 1), 256, 0, stream>>>(wd + e * SL, wgtE, wd + e * SL, wgtE, DFF, HID, 1);
      down5_k<<<16 * 16, 256, 0, stream>>>(act, wgtE, cnt, offs, ypair, e, 16, 16, 0);
    }
    combine_k<<<(N_TOK * HID / 4) / 256, 256, 0, stream>>>(ypair, tok_slot, topk_w, out);
  }
}